// Round 6
// baseline (300.819 us; speedup 1.0000x reference)
//
#include <hip/hip_runtime.h>

// SkeletalPool: out[b, j, c, t] = 0.5f * (x[b, idx0(j), c, t] + x[b, idx1(j), c, t])
//   x:   [32, 31, 64, 4096] fp32 (1.04 GB)
//   out: [32, 16, 64, 4096] fp32 (0.54 GB)
//   idx0(j) = j==0 ? 0 : 2j-1 ; idx1(j) = 2j
//
// R6: burst-length ladder: R4 4KB (+6%), R5 8KB (+5%). Now 16KB contiguous
// per plane per wave iteration (U=16, 32 NT loads in flight), grid halved to
// 512 blocks (2048 waves) keeping the aggregate concurrent window ~32MB.

typedef float f32x4 __attribute__((ext_vector_type(4)));

#define U 16  // float4s per lane per chunk; wave chunk = 64*U*16B = 16KB/plane

__global__ __launch_bounds__(256) void skel_pool_kernel(
    const f32x4* __restrict__ x, f32x4* __restrict__ out,
    int nchunks, int nwaves) {
    int gtid = blockIdx.x * blockDim.x + threadIdx.x;
    int wave = gtid >> 6;
    int lane = gtid & 63;

    for (int k = wave; k < nchunks; k += nwaves) {
        int plane = k >> 6;                    // 64 chunks per 1MiB plane
        int remb  = ((k & 63) << 10) + lane;   // float4 offset in plane
        int b     = plane >> 4;
        int j     = plane & 15;
        int j1    = j << 1;               // 2j
        int j0    = j1 - (j != 0);        // max(2j-1, 0)
        int ib    = b * 31;

        const f32x4* pa = x + ((ib + j0) << 16) + remb;
        const f32x4* pc = x + ((ib + j1) << 16) + remb;
        f32x4*       po = out + (plane << 16) + remb;

        f32x4 a[U], c[U];
#pragma unroll
        for (int u = 0; u < U; ++u) a[u] = __builtin_nontemporal_load(pa + u * 64);
#pragma unroll
        for (int u = 0; u < U; ++u) c[u] = __builtin_nontemporal_load(pc + u * 64);
#pragma unroll
        for (int u = 0; u < U; ++u)
            __builtin_nontemporal_store((a[u] + c[u]) * 0.5f, po + u * 64);
    }
}

extern "C" void kernel_launch(void* const* d_in, const int* in_sizes, int n_in,
                              void* d_out, int out_size, void* d_ws, size_t ws_size,
                              hipStream_t stream) {
    const f32x4* x = (const f32x4*)d_in[0];
    f32x4* out = (f32x4*)d_out;
    int total4  = out_size / 4;          // 2^25 f32x4
    int nchunks = total4 >> 10;          // 1024 f32x4 (16KB) per chunk = 32768
    const int block = 256;
    int blocks = 512;                    // 2048 waves -> 16 chunks per wave
    int nwaves = blocks * (block / 64);
    skel_pool_kernel<<<blocks, block, 0, stream>>>(x, out, nchunks, nwaves);
}

// Round 7
// 297.603 us; speedup vs baseline: 1.0108x; 1.0108x over previous
//
#include <hip/hip_runtime.h>

// SkeletalPool: out[b, j, c, t] = 0.5f * (x[b, idx0(j), c, t] + x[b, idx1(j), c, t])
//   x:   [32, 31, 64, 4096] fp32 (1.04 GB)
//   out: [32, 16, 64, 4096] fp32 (0.54 GB)
//   idx0(j) = j==0 ? 0 : 2j-1 ; idx1(j) = 2j
//
// R7 (disambiguation): R6 regressed but changed burst AND wave count together.
// Keep U=16 (16KB burst/plane), restore 1024 blocks = 4096 waves (16/CU).
// vs R6: only wave count changes. vs R5: only burst length changes.

typedef float f32x4 __attribute__((ext_vector_type(4)));

#define U 16  // float4s per lane per chunk; wave chunk = 64*U*16B = 16KB/plane

__global__ __launch_bounds__(256) void skel_pool_kernel(
    const f32x4* __restrict__ x, f32x4* __restrict__ out,
    int nchunks, int nwaves) {
    int gtid = blockIdx.x * blockDim.x + threadIdx.x;
    int wave = gtid >> 6;
    int lane = gtid & 63;

    for (int k = wave; k < nchunks; k += nwaves) {
        int plane = k >> 6;                    // 64 chunks per 1MiB plane
        int remb  = ((k & 63) << 10) + lane;   // float4 offset in plane
        int b     = plane >> 4;
        int j     = plane & 15;
        int j1    = j << 1;               // 2j
        int j0    = j1 - (j != 0);        // max(2j-1, 0)
        int ib    = b * 31;

        const f32x4* pa = x + ((ib + j0) << 16) + remb;
        const f32x4* pc = x + ((ib + j1) << 16) + remb;
        f32x4*       po = out + (plane << 16) + remb;

        f32x4 a[U], c[U];
#pragma unroll
        for (int u = 0; u < U; ++u) a[u] = __builtin_nontemporal_load(pa + u * 64);
#pragma unroll
        for (int u = 0; u < U; ++u) c[u] = __builtin_nontemporal_load(pc + u * 64);
#pragma unroll
        for (int u = 0; u < U; ++u)
            __builtin_nontemporal_store((a[u] + c[u]) * 0.5f, po + u * 64);
    }
}

extern "C" void kernel_launch(void* const* d_in, const int* in_sizes, int n_in,
                              void* d_out, int out_size, void* d_ws, size_t ws_size,
                              hipStream_t stream) {
    const f32x4* x = (const f32x4*)d_in[0];
    f32x4* out = (f32x4*)d_out;
    int total4  = out_size / 4;          // 2^25 f32x4
    int nchunks = total4 >> 10;          // 1024 f32x4 (16KB) per chunk = 32768
    const int block = 256;
    int blocks = 1024;                   // 4096 waves -> 8 chunks per wave
    int nwaves = blocks * (block / 64);
    skel_pool_kernel<<<blocks, block, 0, stream>>>(x, out, nchunks, nwaves);
}

// Round 8
// 278.704 us; speedup vs baseline: 1.0793x; 1.0678x over previous
//
#include <hip/hip_runtime.h>

// SkeletalPool: out[b, j, c, t] = 0.5f * (x[b, idx0(j), c, t] + x[b, idx1(j), c, t])
//   x:   [32, 31, 64, 4096] fp32 (1.04 GB)
//   out: [32, 16, 64, 4096] fp32 (0.54 GB)
//   idx0(j) = j==0 ? 0 : 2j-1 ; idx1(j) = 2j
//
// R8: R5 config (8KB burst/plane, U=8, 1024 blocks = 4096 waves) was best
// (281us, 5.61 TB/s). Burst ladder saturated (16KB regressed, R6/R7).
// Residuals: (1) j==0 reads plane 0 twice; with NT loads that's ~32MiB of
// duplicate HBM fetch -> special-case as pure copy. (2) pair-interleave
// a[u],c[u] loads so stores' vmcnt deps resolve progressively.

typedef float f32x4 __attribute__((ext_vector_type(4)));

#define U 8  // float4s per lane per chunk; wave chunk = 64*U*16B = 8KB/plane

__global__ __launch_bounds__(256) void skel_pool_kernel(
    const f32x4* __restrict__ x, f32x4* __restrict__ out,
    int nchunks, int nwaves) {
    int gtid = blockIdx.x * blockDim.x + threadIdx.x;
    int wave = gtid >> 6;
    int lane = gtid & 63;

    for (int k = wave; k < nchunks; k += nwaves) {
        int plane = k >> 7;                   // 128 chunks per 1MiB plane
        int remb  = ((k & 127) << 9) + lane;  // float4 offset in plane
        int b     = plane >> 4;
        int j     = plane & 15;
        int j1    = j << 1;               // 2j
        int j0    = j1 - (j != 0);        // max(2j-1, 0)
        int ib    = b * 31;

        const f32x4* pa = x + ((ib + j0) << 16) + remb;
        const f32x4* pc = x + ((ib + j1) << 16) + remb;
        f32x4*       po = out + (plane << 16) + remb;

        if (j == 0) {
            // (x0 + x0) * 0.5 == x0 exactly: pure copy, skip duplicate load.
            f32x4 a[U];
#pragma unroll
            for (int u = 0; u < U; ++u)
                a[u] = __builtin_nontemporal_load(pa + u * 64);
#pragma unroll
            for (int u = 0; u < U; ++u)
                __builtin_nontemporal_store(a[u], po + u * 64);
        } else {
            f32x4 a[U], c[U];
#pragma unroll
            for (int u = 0; u < U; ++u) {     // pair-interleaved loads
                a[u] = __builtin_nontemporal_load(pa + u * 64);
                c[u] = __builtin_nontemporal_load(pc + u * 64);
            }
#pragma unroll
            for (int u = 0; u < U; ++u)
                __builtin_nontemporal_store((a[u] + c[u]) * 0.5f, po + u * 64);
        }
    }
}

extern "C" void kernel_launch(void* const* d_in, const int* in_sizes, int n_in,
                              void* d_out, int out_size, void* d_ws, size_t ws_size,
                              hipStream_t stream) {
    const f32x4* x = (const f32x4*)d_in[0];
    f32x4* out = (f32x4*)d_out;
    int total4  = out_size / 4;          // 2^25 f32x4
    int nchunks = total4 >> 9;           // 512 f32x4 (8KB) per chunk = 65536
    const int block = 256;
    int blocks = 1024;                   // 4096 waves -> 16 chunks per wave
    int nwaves = blocks * (block / 64);
    skel_pool_kernel<<<blocks, block, 0, stream>>>(x, out, nchunks, nwaves);
}

// Round 9
// 276.243 us; speedup vs baseline: 1.0890x; 1.0089x over previous
//
#include <hip/hip_runtime.h>

// SkeletalPool: out[b, j, c, t] = 0.5f * (x[b, idx0(j), c, t] + x[b, idx1(j), c, t])
//   x:   [32, 31, 64, 4096] fp32 (1.04 GB)
//   out: [32, 16, 64, 4096] fp32 (0.54 GB)
//   idx0(j) = j==0 ? 0 : 2j-1 ; idx1(j) = 2j
//
// R9 (last grid cell): R8 = 8KB burst @ 4096 waves = 278.7us (5.66 TB/s, 90%
// of copy ceiling). Grid so far: 4KB@8192w=295, 8KB@4096w=279, 16KB@{4096,
// 2048}w=298/301. Single-variable test: 8KB @ 8192 waves (full occupancy).
// Keeps R8's j==0 dedup + pair-interleaved loads.

typedef float f32x4 __attribute__((ext_vector_type(4)));

#define U 8  // float4s per lane per chunk; wave chunk = 64*U*16B = 8KB/plane

__global__ __launch_bounds__(256) void skel_pool_kernel(
    const f32x4* __restrict__ x, f32x4* __restrict__ out,
    int nchunks, int nwaves) {
    int gtid = blockIdx.x * blockDim.x + threadIdx.x;
    int wave = gtid >> 6;
    int lane = gtid & 63;

    for (int k = wave; k < nchunks; k += nwaves) {
        int plane = k >> 7;                   // 128 chunks per 1MiB plane
        int remb  = ((k & 127) << 9) + lane;  // float4 offset in plane
        int b     = plane >> 4;
        int j     = plane & 15;
        int j1    = j << 1;               // 2j
        int j0    = j1 - (j != 0);        // max(2j-1, 0)
        int ib    = b * 31;

        const f32x4* pa = x + ((ib + j0) << 16) + remb;
        const f32x4* pc = x + ((ib + j1) << 16) + remb;
        f32x4*       po = out + (plane << 16) + remb;

        if (j == 0) {
            // (x0 + x0) * 0.5 == x0 exactly: pure copy, skip duplicate load.
            f32x4 a[U];
#pragma unroll
            for (int u = 0; u < U; ++u)
                a[u] = __builtin_nontemporal_load(pa + u * 64);
#pragma unroll
            for (int u = 0; u < U; ++u)
                __builtin_nontemporal_store(a[u], po + u * 64);
        } else {
            f32x4 a[U], c[U];
#pragma unroll
            for (int u = 0; u < U; ++u) {     // pair-interleaved loads
                a[u] = __builtin_nontemporal_load(pa + u * 64);
                c[u] = __builtin_nontemporal_load(pc + u * 64);
            }
#pragma unroll
            for (int u = 0; u < U; ++u)
                __builtin_nontemporal_store((a[u] + c[u]) * 0.5f, po + u * 64);
        }
    }
}

extern "C" void kernel_launch(void* const* d_in, const int* in_sizes, int n_in,
                              void* d_out, int out_size, void* d_ws, size_t ws_size,
                              hipStream_t stream) {
    const f32x4* x = (const f32x4*)d_in[0];
    f32x4* out = (f32x4*)d_out;
    int total4  = out_size / 4;          // 2^25 f32x4
    int nchunks = total4 >> 9;           // 512 f32x4 (8KB) per chunk = 65536
    const int block = 256;
    int blocks = 2048;                   // 8192 waves -> 8 chunks per wave
    int nwaves = blocks * (block / 64);
    skel_pool_kernel<<<blocks, block, 0, stream>>>(x, out, nchunks, nwaves);
}